// Round 2
// baseline (66.104 us; speedup 1.0000x reference)
//
#include <hip/hip_runtime.h>
#include <math.h>

#define DIM 128
#define PSTRIDE 132          // per-partial floats: m, l, pad, pad, acc[128] (16B-aligned acc)
#define NEG_BIG (-1e30f)

// ---------------------------------------------------------------------------
// Pass 1: each 32-lane half-wave ("stream") owns a strided set of rows.
// Lane vlane holds elements [4*vlane .. 4*vlane+3] (float4) of query/key/value.
// Rows are processed in batches of 4: four independent 5-step shuffle reduces
// (ILP), then ONE online-softmax max/rescale per batch. Halves merge at the
// end via lane^32 shuffles. One partial (m, l, acc[128]) per wave -> ws.
// ---------------------------------------------------------------------------
__global__ __launch_bounds__(256) void nd_pass1(const float* __restrict__ query,
                                                const float* __restrict__ keys,
                                                const float* __restrict__ values,
                                                float* __restrict__ ws,
                                                int nrows, int P) {
    const int tid   = threadIdx.x;
    const int lane  = tid & 63;
    const int vlane = lane & 31;
    const int half  = lane >> 5;
    const int p     = blockIdx.x * (blockDim.x >> 6) + (tid >> 6);   // wave id
    const int S     = P * 2;                                          // streams
    const int strm  = p * 2 + half;

    const float4 q = *reinterpret_cast<const float4*>(query + vlane * 4);

    float  m = NEG_BIG;
    float  l = 0.f;
    float4 acc = make_float4(0.f, 0.f, 0.f, 0.f);

    for (int r0 = strm; r0 < nrows; r0 += 4 * S) {
        float  logit[4];
        float4 v[4];
        #pragma unroll
        for (int j = 0; j < 4; ++j) {
            const int  row = r0 + j * S;
            const bool ok  = row < nrows;
            const int  rr  = ok ? row : 0;
            const float4 kv = *reinterpret_cast<const float4*>(keys   + (size_t)rr * DIM + vlane * 4);
            v[j]            = *reinterpret_cast<const float4*>(values + (size_t)rr * DIM + vlane * 4);
            float s = fabsf(kv.x - q.x) + fabsf(kv.y - q.y)
                    + fabsf(kv.z - q.z) + fabsf(kv.w - q.w);
            #pragma unroll
            for (int off = 16; off > 0; off >>= 1)
                s += __shfl_xor(s, off, 64);          // stays within 32-lane half
            logit[j] = ok ? -s : NEG_BIG;             // invalid -> weight exp()==0
        }

        const float bm   = fmaxf(fmaxf(logit[0], logit[1]), fmaxf(logit[2], logit[3]));
        const float newm = fmaxf(m, bm);              // j==0 always valid -> finite
        const float scale = __expf(m - newm);
        float w[4];
        #pragma unroll
        for (int j = 0; j < 4; ++j)
            w[j] = __expf(logit[j] - newm);

        l = l * scale + ((w[0] + w[1]) + (w[2] + w[3]));
        acc.x = acc.x * scale + w[0]*v[0].x + w[1]*v[1].x + w[2]*v[2].x + w[3]*v[3].x;
        acc.y = acc.y * scale + w[0]*v[0].y + w[1]*v[1].y + w[2]*v[2].y + w[3]*v[3].y;
        acc.z = acc.z * scale + w[0]*v[0].z + w[1]*v[1].z + w[2]*v[2].z + w[3]*v[3].z;
        acc.w = acc.w * scale + w[0]*v[0].w + w[1]*v[1].w + w[2]*v[2].w + w[3]*v[3].w;
        m = newm;
    }

    // Merge the two half-wave streams (each uniform within its half).
    const float m2 = __shfl_xor(m, 32, 64);
    const float l2 = __shfl_xor(l, 32, 64);
    float4 a2;
    a2.x = __shfl_xor(acc.x, 32, 64);
    a2.y = __shfl_xor(acc.y, 32, 64);
    a2.z = __shfl_xor(acc.z, 32, 64);
    a2.w = __shfl_xor(acc.w, 32, 64);
    const float M  = fmaxf(m, m2);
    const float e1 = __expf(m  - M);
    const float e2 = __expf(m2 - M);
    const float L  = l * e1 + l2 * e2;
    float4 A;
    A.x = acc.x * e1 + a2.x * e2;
    A.y = acc.y * e1 + a2.y * e2;
    A.z = acc.z * e1 + a2.z * e2;
    A.w = acc.w * e1 + a2.w * e2;

    float* wp = ws + (size_t)p * PSTRIDE;
    if (lane == 0) { wp[0] = M; wp[1] = L; }
    if (half == 0)
        *reinterpret_cast<float4*>(wp + 4 + vlane * 4) = A;
}

// ---------------------------------------------------------------------------
// Pass 2: each block merges 64 consecutive partials into one partial.
//   M = max m_p; e_p = exp(m_p - M); l = sum l_p e_p; acc[d] = sum acc_p[d] e_p
// ---------------------------------------------------------------------------
__global__ __launch_bounds__(256) void nd_pass2(const float* __restrict__ ws,
                                                float* __restrict__ ws2) {
    __shared__ float sh_e[64];
    __shared__ float sh_red[256];
    __shared__ float shM, shL;
    const int tid  = threadIdx.x;
    const int base = blockIdx.x * 64;

    if (tid < 64) {
        const float mm = ws[(size_t)(base + tid) * PSTRIDE];
        float r = mm;
        #pragma unroll
        for (int off = 32; off > 0; off >>= 1)
            r = fmaxf(r, __shfl_xor(r, off, 64));
        const float e = __expf(mm - r);
        sh_e[tid] = e;
        float lp = ws[(size_t)(base + tid) * PSTRIDE + 1] * e;
        #pragma unroll
        for (int off = 32; off > 0; off >>= 1)
            lp += __shfl_xor(lp, off, 64);
        if (tid == 0) { shM = r; shL = lp; }
    }
    __syncthreads();

    const int d = tid & 127, g = tid >> 7;
    float o = 0.f;
    for (int p = g; p < 64; p += 2)
        o += ws[(size_t)(base + p) * PSTRIDE + 4 + d] * sh_e[p];
    sh_red[tid] = o;
    __syncthreads();

    if (tid < 128) {
        float* wp = ws2 + (size_t)blockIdx.x * PSTRIDE;
        if (tid == 0) { wp[0] = shM; wp[1] = shL; }
        wp[4 + tid] = sh_red[tid] + sh_red[tid + 128];
    }
}

// ---------------------------------------------------------------------------
// Pass 3: single block merges the B2 (<=128) level-2 partials and normalizes.
// ---------------------------------------------------------------------------
__global__ __launch_bounds__(256) void nd_pass3(const float* __restrict__ ws2,
                                                float* __restrict__ out, int B2) {
    __shared__ float sh_e[128];
    __shared__ float sh_red[256];
    __shared__ float shL;
    const int tid = threadIdx.x;

    if (tid < 64) {
        const float m0 = (tid      < B2) ? ws2[(size_t)tid * PSTRIDE]        : NEG_BIG;
        const float m1 = (tid + 64 < B2) ? ws2[(size_t)(tid + 64) * PSTRIDE] : NEG_BIG;
        float r = fmaxf(m0, m1);
        #pragma unroll
        for (int off = 32; off > 0; off >>= 1)
            r = fmaxf(r, __shfl_xor(r, off, 64));
        const float e0 = (tid      < B2) ? __expf(m0 - r) : 0.f;
        const float e1 = (tid + 64 < B2) ? __expf(m1 - r) : 0.f;
        sh_e[tid] = e0; sh_e[tid + 64] = e1;
        float lp = 0.f;
        if (tid      < B2) lp += ws2[(size_t)tid * PSTRIDE + 1] * e0;
        if (tid + 64 < B2) lp += ws2[(size_t)(tid + 64) * PSTRIDE + 1] * e1;
        #pragma unroll
        for (int off = 32; off > 0; off >>= 1)
            lp += __shfl_xor(lp, off, 64);
        if (tid == 0) shL = lp;
    }
    __syncthreads();

    const int d = tid & 127, g = tid >> 7;
    float o = 0.f;
    for (int p = g; p < B2; p += 2)
        o += ws2[(size_t)p * PSTRIDE + 4 + d] * sh_e[p];
    sh_red[tid] = o;
    __syncthreads();

    if (tid < 128)
        out[tid] = (sh_red[tid] + sh_red[tid + 128]) / shL;
}

extern "C" void kernel_launch(void* const* d_in, const int* in_sizes, int n_in,
                              void* d_out, int out_size, void* d_ws, size_t ws_size,
                              hipStream_t stream) {
    const float* query  = (const float*)d_in[0];
    const float* keys   = (const float*)d_in[1];
    const float* values = (const float*)d_in[2];
    float* out = (float*)d_out;
    float* ws  = (float*)d_ws;

    const int nrows = in_sizes[1] / DIM;

    // P1 waves in pass 1; fit (P1 + P1/64) partials of PSTRIDE floats in ws.
    int P1 = 8192;
    const size_t cap = ws_size / (PSTRIDE * sizeof(float));
    while ((size_t)(P1 + P1 / 64) > cap && P1 > 256) P1 >>= 1;

    const int blocks1 = P1 / 4;        // 4 waves (256 threads) per block
    const int B2      = P1 / 64;       // level-2 partial count (<=128)
    float* ws2 = ws + (size_t)P1 * PSTRIDE;

    nd_pass1<<<blocks1, 256, 0, stream>>>(query, keys, values, ws, nrows, P1);
    nd_pass2<<<B2, 256, 0, stream>>>(ws, ws2);
    nd_pass3<<<1, 256, 0, stream>>>(ws2, out, B2);
}